// Round 14
// baseline (129.213 us; speedup 1.0000x reference)
//
#include <hip/hip_runtime.h>

// positions [N,3] f32, node_feat [N,1] f32, w0 [1] f32, w1 [3] f32,
// edge_src [E] i32, edge_dst [E] i32  ->  out [N,4] f32
//
// R14 = R12 (best, 117.6 us) with phaseB's LDS window preload dropped
// (dst gathers hit the L1/L2-resident pos4 window directly; saves a
// barrier + preload traffic, LDS 48->16 KB -> 4 blocks/CU).
// R13's deterministic-offset restructure regressed (fragmented phaseB
// reads) and is reverted.
//
// Measured constraints that shaped this design:
//  - global atomics: ~22 G ops/s hard cap, 32 B EA transaction each,
//    scope/payload-insensitive (R1-R4) -> zero data-path global atomics.
//  - ~87 us fixed harness reset (256 MB ws poison) dominates wall time;
//    kernel sum ~30 us vs ~15 us streaming floor.
//
// Record (u32): local(11b)<<17 | src(17b).   [needs n_nodes < 131072]
// Accum cell (u64): fx<<48 | fy<<32 | fz<<16 | count, f? = 128+round(sh*128).
//   Worst per-(node,shard) count ~deg_max(~70) -> field sums <= 17.9k
//   << 65536, no carry.  Decode: sum_sh = F/128 - count.
//   (absmax 7.8e-3, stable R3-R13)

#define EPS 1e-12f
#define FSCALE 128.0f
#define FBIAS 128
#define CHUNK_SHIFT 11
#define CHUNK 2048
#define NCHUNK_MAX 64
#define BLKA 512
#define TPA 8
#define NSTAGE (BLKA * TPA)
#define BLKB 512
#define SHARDS 8

// ---- repack pos->float4 (padded, tail zeroed) + zero gcnt ---------------
__global__ void repack_pos(const float* __restrict__ pos,
                           float4* __restrict__ pos4,
                           unsigned* __restrict__ gcnt,
                           int n_nodes, int padded) {
    int n = blockIdx.x * blockDim.x + threadIdx.x;
    if (n < SHARDS * NCHUNK_MAX) gcnt[n] = 0;
    if (n >= padded) return;
    float4 p = make_float4(0.f, 0.f, 0.f, 0.f);
    if (n < n_nodes) {
        p.x = pos[3 * n + 0];
        p.y = pos[3 * n + 1];
        p.z = pos[3 * n + 2];
    }
    pos4[n] = p;
}

// ---- Phase A: pure integer binning (no pos access, no FP) ---------------
__global__ __launch_bounds__(BLKA) void phaseA(
        const int* __restrict__ dst,
        const int* __restrict__ src,
        unsigned* __restrict__ gcnt,                 // [SHARDS][NCHUNK_MAX]
        unsigned* __restrict__ recs,                 // [SHARDS*n_chunk][capx]
        int n_edges, int capx, int n_chunk) {
    __shared__ unsigned stage[NSTAGE];               // 16 KB
    __shared__ unsigned h[NCHUNK_MAX];
    __shared__ unsigned pref[NCHUNK_MAX + 1];
    __shared__ unsigned gbase[NCHUNK_MAX];
    int tid = threadIdx.x;
    int shard = (int)blockIdx.x & (SHARDS - 1);
    if (tid < n_chunk) h[tid] = 0;
    __syncthreads();

    long e0 = (long)blockIdx.x * NSTAGE;
    unsigned rec[TPA];
    int ch[TPA];
    unsigned rank[TPA];
    bool val[TPA];
#pragma unroll
    for (int t = 0; t < TPA; ++t) {
        long j = e0 + (long)t * BLKA + tid;
        val[t] = (j < n_edges);
        if (val[t]) {
            int d = dst[j];
            int s = src[j];
            ch[t] = d >> CHUNK_SHIFT;
            rec[t] = ((unsigned)(d & (CHUNK - 1)) << 17) | (unsigned)s;
            rank[t] = atomicAdd(&h[ch[t]], 1u);
        }
    }
    __syncthreads();
    // wave-0 parallel exclusive scan of chunk counts (n_chunk <= 64)
    if (tid < 64) {
        unsigned v = (tid < n_chunk) ? h[tid] : 0u;
#pragma unroll
        for (int ofs = 1; ofs < 64; ofs <<= 1) {
            unsigned u = __shfl_up(v, ofs, 64);
            if (tid >= ofs) v += u;
        }
        if (tid == 0) pref[0] = 0;
        if (tid < n_chunk) pref[tid + 1] = v;        // inclusive -> pref[c+1]
    }
    if (tid < n_chunk)
        gbase[tid] = h[tid] ? atomicAdd(&gcnt[shard * NCHUNK_MAX + tid], h[tid]) : 0u;
    __syncthreads();
#pragma unroll
    for (int t = 0; t < TPA; ++t)
        if (val[t]) stage[pref[ch[t]] + rank[t]] = rec[t];
    __syncthreads();
    unsigned total = pref[n_chunk];
    for (unsigned i = tid; i < total; i += BLKA) {
        int lo = 0, hi = n_chunk - 1;
        while (lo < hi) {                 // largest c with pref[c] <= i
            int mid = (lo + hi + 1) >> 1;
            if (pref[mid] <= i) lo = mid; else hi = mid - 1;
        }
        unsigned idx = gbase[lo] + (i - pref[lo]);
        if (idx < (unsigned)capx)
            recs[(size_t)(shard * n_chunk + lo) * (unsigned)capx + idx] = stage[i];
    }
}

// ---- Phase B: per (chunk, shard): SH compute + LDS accumulate -----------
__global__ __launch_bounds__(BLKB) void phaseB(
        const unsigned* __restrict__ gcnt,
        const unsigned* __restrict__ recs,
        const float4* __restrict__ pos4,
        unsigned long long* __restrict__ accR,       // [SHARDS][padded]
        int capx, int n_chunk, int padded) {
    __shared__ unsigned long long acc[CHUNK];        // 16 KB
    int c     = (int)blockIdx.x % n_chunk;
    int shard = (int)blockIdx.x / n_chunk;
    int base  = c << CHUNK_SHIFT;

    for (int i = threadIdx.x; i < CHUNK; i += BLKB) acc[i] = 0ull;
    __syncthreads();

    unsigned cnt = gcnt[shard * NCHUNK_MAX + c];
    if (cnt > (unsigned)capx) cnt = (unsigned)capx;
    const unsigned* bucket = recs + (size_t)(shard * n_chunk + c) * (unsigned)capx;
    for (unsigned j = threadIdx.x; j < cnt; j += BLKB) {
        unsigned r = bucket[j];
        unsigned s = r & 0x1FFFFu;
        unsigned local = r >> 17;
        float4 ps = pos4[s];            // random gather, L2-resident table
        float4 pd = pos4[base + local]; // random within 32 KB L1-hot window
        float rx = pd.x - ps.x;
        float ry = pd.y - ps.y;
        float rz = pd.z - ps.z;
        float inv = 1.0f / fmaxf(sqrtf(rx * rx + ry * ry + rz * rz), EPS);
        unsigned fx = (unsigned)(FBIAS + (int)rintf(rx * inv * FSCALE));
        unsigned fy = (unsigned)(FBIAS + (int)rintf(ry * inv * FSCALE));
        unsigned fz = (unsigned)(FBIAS + (int)rintf(rz * inv * FSCALE));
        unsigned long long p = ((unsigned long long)fx << 48)
                             | ((unsigned long long)fy << 32)
                             | ((unsigned long long)fz << 16) | 1ull;
        atomicAdd(&acc[local], p);
    }
    __syncthreads();

    unsigned long long* row = accR + (size_t)shard * (unsigned)padded + base;
    for (int i = threadIdx.x; i < CHUNK; i += BLKB) row[i] = acc[i];
}

// ---- Finalize: merge SHARDS replicas, decode, weight --------------------
__global__ void finalize_binned(const unsigned long long* __restrict__ accR,
                                const float* __restrict__ feat,
                                const float* __restrict__ w0,
                                const float* __restrict__ w1,
                                float* __restrict__ out,
                                int n_nodes, int padded) {
    int n = blockIdx.x * blockDim.x + threadIdx.x;
    if (n >= n_nodes) return;
    int Fx = 0, Fy = 0, Fz = 0, C = 0;
    for (int s = 0; s < SHARDS; ++s) {
        unsigned long long v = accR[(size_t)s * (unsigned)padded + (unsigned)n];
        Fx += (int)(v >> 48);
        Fy += (int)((v >> 32) & 0xffffull);
        Fz += (int)((v >> 16) & 0xffffull);
        C  += (int)(v & 0xffffull);
    }
    float c = (float)C;
    float rd = 1.0f / fmaxf(c, 1.0f);
    float sx = (float)Fx * (1.0f / FSCALE) - c;
    float sy = (float)Fy * (1.0f / FSCALE) - c;
    float sz = (float)Fz * (1.0f / FSCALE) - c;
    float f = feat[n];
    float4 o;
    o.x = w0[0] * f * c * rd;
    o.y = w1[0] * f * sx * rd;
    o.z = w1[1] * f * sy * rd;
    o.w = w1[2] * f * sz * rd;
    ((float4*)out)[n] = o;
}

// ---- Fallback (R3, known-good) ------------------------------------------
__global__ void edge_kernel_agent(const float* __restrict__ pos,
                                  const int* __restrict__ dst,
                                  const int* __restrict__ src,
                                  unsigned long long* __restrict__ acc,
                                  int n_edges, int n_nodes, int rmask) {
    int i = blockIdx.x * blockDim.x + threadIdx.x;
    if (i >= n_edges) return;
    int s = src[i];
    int d = dst[i];
    float rx = pos[3 * d + 0] - pos[3 * s + 0];
    float ry = pos[3 * d + 1] - pos[3 * s + 1];
    float rz = pos[3 * d + 2] - pos[3 * s + 2];
    float inv = 1.0f / fmaxf(sqrtf(rx * rx + ry * ry + rz * rz), EPS);
    unsigned fx = (unsigned)(FBIAS + (int)rintf(rx * inv * FSCALE));
    unsigned fy = (unsigned)(FBIAS + (int)rintf(ry * inv * FSCALE));
    unsigned fz = (unsigned)(FBIAS + (int)rintf(rz * inv * FSCALE));
    unsigned long long p = ((unsigned long long)fx << 48)
                         | ((unsigned long long)fy << 32)
                         | ((unsigned long long)fz << 16) | 1ull;
    unsigned r = (unsigned)blockIdx.x & (unsigned)rmask;
    atomicAdd(acc + (size_t)r * (unsigned)n_nodes + (unsigned)d, p);
}

__global__ void finalize_flat(const unsigned long long* __restrict__ acc,
                              const float* __restrict__ feat,
                              const float* __restrict__ w0,
                              const float* __restrict__ w1,
                              float* __restrict__ out,
                              int n_nodes, int R) {
    int n = blockIdx.x * blockDim.x + threadIdx.x;
    if (n >= n_nodes) return;
    int Fx = 0, Fy = 0, Fz = 0, C = 0;
    for (int r = 0; r < R; ++r) {
        unsigned long long v = acc[(size_t)r * n_nodes + n];
        Fx += (int)(v >> 48);
        Fy += (int)((v >> 32) & 0xffffull);
        Fz += (int)((v >> 16) & 0xffffull);
        C  += (int)(v & 0xffffull);
    }
    float c = (float)C;
    float rd = 1.0f / fmaxf(c, 1.0f);
    float sx = (float)Fx * (1.0f / FSCALE) - c;
    float sy = (float)Fy * (1.0f / FSCALE) - c;
    float sz = (float)Fz * (1.0f / FSCALE) - c;
    float f = feat[n];
    float4 o;
    o.x = w0[0] * f * c * rd;
    o.y = w1[0] * f * sx * rd;
    o.z = w1[1] * f * sy * rd;
    o.w = w1[2] * f * sz * rd;
    ((float4*)out)[n] = o;
}

extern "C" void kernel_launch(void* const* d_in, const int* in_sizes, int n_in,
                              void* d_out, int out_size, void* d_ws, size_t ws_size,
                              hipStream_t stream) {
    const float* pos  = (const float*)d_in[0];
    const float* feat = (const float*)d_in[1];
    const float* w0   = (const float*)d_in[2];
    const float* w1   = (const float*)d_in[3];
    const int* esrc   = (const int*)d_in[4];
    const int* edst   = (const int*)d_in[5];
    int n_nodes = in_sizes[0] / 3;
    int n_edges = in_sizes[4];

    int n_chunk = (n_nodes + CHUNK - 1) >> CHUNK_SHIFT;      // 49 for 100k
    int padded  = n_chunk * CHUNK;
    // per-(shard,chunk) capacity: expected (~8160) + 1024 (~11 sigma)
    int capx = (int)((long)n_edges / ((long)SHARDS * n_chunk) + 1024);

    size_t off_pos4 = 0;
    size_t pos4_bytes = (size_t)padded * sizeof(float4);
    size_t off_gcnt = (pos4_bytes + 255) & ~(size_t)255;
    size_t gcnt_bytes = (size_t)SHARDS * NCHUNK_MAX * sizeof(unsigned);
    size_t off_recs = off_gcnt + ((gcnt_bytes + 255) & ~(size_t)255);
    size_t recs_bytes = (size_t)SHARDS * n_chunk * (unsigned)capx * sizeof(unsigned);
    size_t off_accR = off_recs + ((recs_bytes + 255) & ~(size_t)255);
    size_t accR_bytes = (size_t)SHARDS * (unsigned)padded * sizeof(unsigned long long);
    size_t need = off_accR + accR_bytes;

    int nb = 256;
    int ng = (n_nodes + nb - 1) / nb;

    if (n_chunk <= NCHUNK_MAX && n_nodes <= (1 << 17) && ws_size >= need) {
        float4* pos4 = (float4*)((char*)d_ws + off_pos4);
        unsigned* gcnt = (unsigned*)((char*)d_ws + off_gcnt);
        unsigned* recs = (unsigned*)((char*)d_ws + off_recs);
        unsigned long long* accR = (unsigned long long*)((char*)d_ws + off_accR);

        int rg = (padded + nb - 1) / nb;
        repack_pos<<<rg, nb, 0, stream>>>(pos, pos4, gcnt, n_nodes, padded);

        int ga = (int)((n_edges + (long)NSTAGE - 1) / (long)NSTAGE);
        phaseA<<<ga, BLKA, 0, stream>>>(edst, esrc, gcnt, recs,
                                        n_edges, capx, n_chunk);
        phaseB<<<n_chunk * SHARDS, BLKB, 0, stream>>>(gcnt, recs, pos4, accR,
                                                      capx, n_chunk, padded);
        finalize_binned<<<ng, nb, 0, stream>>>(accR, feat, w0, w1,
                                               (float*)d_out, n_nodes, padded);
    } else {
        int R = 4;
        while (R > 1 && (size_t)R * n_nodes * sizeof(unsigned long long) > ws_size) R >>= 1;
        unsigned long long* acc = (unsigned long long*)d_ws;
        hipMemsetAsync(acc, 0, (size_t)R * n_nodes * sizeof(unsigned long long), stream);
        int eb = 256;
        int eg = (n_edges + eb - 1) / eb;
        edge_kernel_agent<<<eg, eb, 0, stream>>>(pos, edst, esrc, acc,
                                                 n_edges, n_nodes, R - 1);
        finalize_flat<<<ng, nb, 0, stream>>>(acc, feat, w0, w1,
                                             (float*)d_out, n_nodes, R);
    }
}

// Round 15
// 119.508 us; speedup vs baseline: 1.0812x; 1.0812x over previous
//
#include <hip/hip_runtime.h>

// positions [N,3] f32, node_feat [N,1] f32, w0 [1] f32, w1 [3] f32,
// edge_src [E] i32, edge_dst [E] i32  ->  out [N,4] f32
//
// R15 = exact revert to R12 (best measured: 117.6 us).
// Deviations tried and REGRESSED — do not repeat:
//  - R8: cooperative single-kernel fusion (316 us; halved phaseA occupancy,
//    serialized phases; fixed ~87 us overhead is harness reset, not gaps).
//  - R13: deterministic per-block record slots (123 us; fragmented phaseB
//    reads beat the ~13k allocator atomics it saved).
//  - R14: phaseB window preload dropped (129 us; src gathers thrash L1,
//    the LDS window isolates dst lookups).
// Measured constraints that shaped this design:
//  - global atomics: ~22 G ops/s hard cap, 32 B EA transaction each,
//    scope/payload-insensitive (R1-R4) -> zero data-path global atomics.
//  - ~87 us fixed harness reset (256 MB ws poison at HBM ceiling) dominates
//    wall; kernel sum ~30 us vs ~15 us streaming floor.
//
// Record (u32): local(11b)<<17 | src(17b).   [needs n_nodes < 131072]
// Accum cell (u64): fx<<48 | fy<<32 | fz<<16 | count, f? = 128+round(sh*128).
//   Worst per-(node,shard) count ~deg_max(~70) -> field sums <= 17.9k
//   << 65536, no carry.  Decode: sum_sh = F/128 - count.
//   (absmax 7.8e-3, stable R3-R14)

#define EPS 1e-12f
#define FSCALE 128.0f
#define FBIAS 128
#define CHUNK_SHIFT 11
#define CHUNK 2048
#define NCHUNK_MAX 64
#define BLKA 512
#define TPA 8
#define NSTAGE (BLKA * TPA)
#define BLKB 512
#define SHARDS 8

// ---- repack pos->float4 (padded, tail zeroed) + zero gcnt ---------------
__global__ void repack_pos(const float* __restrict__ pos,
                           float4* __restrict__ pos4,
                           unsigned* __restrict__ gcnt,
                           int n_nodes, int padded) {
    int n = blockIdx.x * blockDim.x + threadIdx.x;
    if (n < SHARDS * NCHUNK_MAX) gcnt[n] = 0;
    if (n >= padded) return;
    float4 p = make_float4(0.f, 0.f, 0.f, 0.f);
    if (n < n_nodes) {
        p.x = pos[3 * n + 0];
        p.y = pos[3 * n + 1];
        p.z = pos[3 * n + 2];
    }
    pos4[n] = p;
}

// ---- Phase A: pure integer binning (no pos access, no FP) ---------------
__global__ __launch_bounds__(BLKA) void phaseA(
        const int* __restrict__ dst,
        const int* __restrict__ src,
        unsigned* __restrict__ gcnt,                 // [SHARDS][NCHUNK_MAX]
        unsigned* __restrict__ recs,                 // [SHARDS*n_chunk][capx]
        int n_edges, int capx, int n_chunk) {
    __shared__ unsigned stage[NSTAGE];               // 16 KB
    __shared__ unsigned h[NCHUNK_MAX];
    __shared__ unsigned pref[NCHUNK_MAX + 1];
    __shared__ unsigned gbase[NCHUNK_MAX];
    int tid = threadIdx.x;
    int shard = (int)blockIdx.x & (SHARDS - 1);
    if (tid < n_chunk) h[tid] = 0;
    __syncthreads();

    long e0 = (long)blockIdx.x * NSTAGE;
    unsigned rec[TPA];
    int ch[TPA];
    unsigned rank[TPA];
    bool val[TPA];
#pragma unroll
    for (int t = 0; t < TPA; ++t) {
        long j = e0 + (long)t * BLKA + tid;
        val[t] = (j < n_edges);
        if (val[t]) {
            int d = dst[j];
            int s = src[j];
            ch[t] = d >> CHUNK_SHIFT;
            rec[t] = ((unsigned)(d & (CHUNK - 1)) << 17) | (unsigned)s;
            rank[t] = atomicAdd(&h[ch[t]], 1u);
        }
    }
    __syncthreads();
    // wave-0 parallel exclusive scan of chunk counts (n_chunk <= 64)
    if (tid < 64) {
        unsigned v = (tid < n_chunk) ? h[tid] : 0u;
#pragma unroll
        for (int ofs = 1; ofs < 64; ofs <<= 1) {
            unsigned u = __shfl_up(v, ofs, 64);
            if (tid >= ofs) v += u;
        }
        if (tid == 0) pref[0] = 0;
        if (tid < n_chunk) pref[tid + 1] = v;        // inclusive -> pref[c+1]
    }
    if (tid < n_chunk)
        gbase[tid] = h[tid] ? atomicAdd(&gcnt[shard * NCHUNK_MAX + tid], h[tid]) : 0u;
    __syncthreads();
#pragma unroll
    for (int t = 0; t < TPA; ++t)
        if (val[t]) stage[pref[ch[t]] + rank[t]] = rec[t];
    __syncthreads();
    unsigned total = pref[n_chunk];
    for (unsigned i = tid; i < total; i += BLKA) {
        int lo = 0, hi = n_chunk - 1;
        while (lo < hi) {                 // largest c with pref[c] <= i
            int mid = (lo + hi + 1) >> 1;
            if (pref[mid] <= i) lo = mid; else hi = mid - 1;
        }
        unsigned idx = gbase[lo] + (i - pref[lo]);
        if (idx < (unsigned)capx)
            recs[(size_t)(shard * n_chunk + lo) * (unsigned)capx + idx] = stage[i];
    }
}

// ---- Phase B: per (chunk, shard): SH compute + LDS accumulate -----------
__global__ __launch_bounds__(BLKB) void phaseB(
        const unsigned* __restrict__ gcnt,
        const unsigned* __restrict__ recs,
        const float4* __restrict__ pos4,
        unsigned long long* __restrict__ accR,       // [SHARDS][padded]
        int capx, int n_chunk, int padded) {
    __shared__ unsigned long long acc[CHUNK];        // 16 KB
    __shared__ float4 posw[CHUNK];                   // 32 KB
    int c     = (int)blockIdx.x % n_chunk;
    int shard = (int)blockIdx.x / n_chunk;
    int base  = c << CHUNK_SHIFT;

    for (int i = threadIdx.x; i < CHUNK; i += BLKB) {
        acc[i] = 0ull;
        posw[i] = pos4[base + i];
    }
    __syncthreads();

    unsigned cnt = gcnt[shard * NCHUNK_MAX + c];
    if (cnt > (unsigned)capx) cnt = (unsigned)capx;
    const unsigned* bucket = recs + (size_t)(shard * n_chunk + c) * (unsigned)capx;
    for (unsigned j = threadIdx.x; j < cnt; j += BLKB) {
        unsigned r = bucket[j];
        unsigned s = r & 0x1FFFFu;
        unsigned local = r >> 17;
        float4 ps = pos4[s];          // random gather, L2-resident table
        float4 pd = posw[local];      // LDS window (isolated from L1 thrash)
        float rx = pd.x - ps.x;
        float ry = pd.y - ps.y;
        float rz = pd.z - ps.z;
        float inv = 1.0f / fmaxf(sqrtf(rx * rx + ry * ry + rz * rz), EPS);
        unsigned fx = (unsigned)(FBIAS + (int)rintf(rx * inv * FSCALE));
        unsigned fy = (unsigned)(FBIAS + (int)rintf(ry * inv * FSCALE));
        unsigned fz = (unsigned)(FBIAS + (int)rintf(rz * inv * FSCALE));
        unsigned long long p = ((unsigned long long)fx << 48)
                             | ((unsigned long long)fy << 32)
                             | ((unsigned long long)fz << 16) | 1ull;
        atomicAdd(&acc[local], p);
    }
    __syncthreads();

    unsigned long long* row = accR + (size_t)shard * (unsigned)padded + base;
    for (int i = threadIdx.x; i < CHUNK; i += BLKB) row[i] = acc[i];
}

// ---- Finalize: merge SHARDS replicas, decode, weight --------------------
__global__ void finalize_binned(const unsigned long long* __restrict__ accR,
                                const float* __restrict__ feat,
                                const float* __restrict__ w0,
                                const float* __restrict__ w1,
                                float* __restrict__ out,
                                int n_nodes, int padded) {
    int n = blockIdx.x * blockDim.x + threadIdx.x;
    if (n >= n_nodes) return;
    int Fx = 0, Fy = 0, Fz = 0, C = 0;
    for (int s = 0; s < SHARDS; ++s) {
        unsigned long long v = accR[(size_t)s * (unsigned)padded + (unsigned)n];
        Fx += (int)(v >> 48);
        Fy += (int)((v >> 32) & 0xffffull);
        Fz += (int)((v >> 16) & 0xffffull);
        C  += (int)(v & 0xffffull);
    }
    float c = (float)C;
    float rd = 1.0f / fmaxf(c, 1.0f);
    float sx = (float)Fx * (1.0f / FSCALE) - c;
    float sy = (float)Fy * (1.0f / FSCALE) - c;
    float sz = (float)Fz * (1.0f / FSCALE) - c;
    float f = feat[n];
    float4 o;
    o.x = w0[0] * f * c * rd;
    o.y = w1[0] * f * sx * rd;
    o.z = w1[1] * f * sy * rd;
    o.w = w1[2] * f * sz * rd;
    ((float4*)out)[n] = o;
}

// ---- Fallback (R3, known-good) ------------------------------------------
__global__ void edge_kernel_agent(const float* __restrict__ pos,
                                  const int* __restrict__ dst,
                                  const int* __restrict__ src,
                                  unsigned long long* __restrict__ acc,
                                  int n_edges, int n_nodes, int rmask) {
    int i = blockIdx.x * blockDim.x + threadIdx.x;
    if (i >= n_edges) return;
    int s = src[i];
    int d = dst[i];
    float rx = pos[3 * d + 0] - pos[3 * s + 0];
    float ry = pos[3 * d + 1] - pos[3 * s + 1];
    float rz = pos[3 * d + 2] - pos[3 * s + 2];
    float inv = 1.0f / fmaxf(sqrtf(rx * rx + ry * ry + rz * rz), EPS);
    unsigned fx = (unsigned)(FBIAS + (int)rintf(rx * inv * FSCALE));
    unsigned fy = (unsigned)(FBIAS + (int)rintf(ry * inv * FSCALE));
    unsigned fz = (unsigned)(FBIAS + (int)rintf(rz * inv * FSCALE));
    unsigned long long p = ((unsigned long long)fx << 48)
                         | ((unsigned long long)fy << 32)
                         | ((unsigned long long)fz << 16) | 1ull;
    unsigned r = (unsigned)blockIdx.x & (unsigned)rmask;
    atomicAdd(acc + (size_t)r * (unsigned)n_nodes + (unsigned)d, p);
}

__global__ void finalize_flat(const unsigned long long* __restrict__ acc,
                              const float* __restrict__ feat,
                              const float* __restrict__ w0,
                              const float* __restrict__ w1,
                              float* __restrict__ out,
                              int n_nodes, int R) {
    int n = blockIdx.x * blockDim.x + threadIdx.x;
    if (n >= n_nodes) return;
    int Fx = 0, Fy = 0, Fz = 0, C = 0;
    for (int r = 0; r < R; ++r) {
        unsigned long long v = acc[(size_t)r * n_nodes + n];
        Fx += (int)(v >> 48);
        Fy += (int)((v >> 32) & 0xffffull);
        Fz += (int)((v >> 16) & 0xffffull);
        C  += (int)(v & 0xffffull);
    }
    float c = (float)C;
    float rd = 1.0f / fmaxf(c, 1.0f);
    float sx = (float)Fx * (1.0f / FSCALE) - c;
    float sy = (float)Fy * (1.0f / FSCALE) - c;
    float sz = (float)Fz * (1.0f / FSCALE) - c;
    float f = feat[n];
    float4 o;
    o.x = w0[0] * f * c * rd;
    o.y = w1[0] * f * sx * rd;
    o.z = w1[1] * f * sy * rd;
    o.w = w1[2] * f * sz * rd;
    ((float4*)out)[n] = o;
}

extern "C" void kernel_launch(void* const* d_in, const int* in_sizes, int n_in,
                              void* d_out, int out_size, void* d_ws, size_t ws_size,
                              hipStream_t stream) {
    const float* pos  = (const float*)d_in[0];
    const float* feat = (const float*)d_in[1];
    const float* w0   = (const float*)d_in[2];
    const float* w1   = (const float*)d_in[3];
    const int* esrc   = (const int*)d_in[4];
    const int* edst   = (const int*)d_in[5];
    int n_nodes = in_sizes[0] / 3;
    int n_edges = in_sizes[4];

    int n_chunk = (n_nodes + CHUNK - 1) >> CHUNK_SHIFT;      // 49 for 100k
    int padded  = n_chunk * CHUNK;
    // per-(shard,chunk) capacity: expected (~8160) + 1024 (~11 sigma)
    int capx = (int)((long)n_edges / ((long)SHARDS * n_chunk) + 1024);

    size_t off_pos4 = 0;
    size_t pos4_bytes = (size_t)padded * sizeof(float4);
    size_t off_gcnt = (pos4_bytes + 255) & ~(size_t)255;
    size_t gcnt_bytes = (size_t)SHARDS * NCHUNK_MAX * sizeof(unsigned);
    size_t off_recs = off_gcnt + ((gcnt_bytes + 255) & ~(size_t)255);
    size_t recs_bytes = (size_t)SHARDS * n_chunk * (unsigned)capx * sizeof(unsigned);
    size_t off_accR = off_recs + ((recs_bytes + 255) & ~(size_t)255);
    size_t accR_bytes = (size_t)SHARDS * (unsigned)padded * sizeof(unsigned long long);
    size_t need = off_accR + accR_bytes;

    int nb = 256;
    int ng = (n_nodes + nb - 1) / nb;

    if (n_chunk <= NCHUNK_MAX && n_nodes <= (1 << 17) && ws_size >= need) {
        float4* pos4 = (float4*)((char*)d_ws + off_pos4);
        unsigned* gcnt = (unsigned*)((char*)d_ws + off_gcnt);
        unsigned* recs = (unsigned*)((char*)d_ws + off_recs);
        unsigned long long* accR = (unsigned long long*)((char*)d_ws + off_accR);

        int rg = (padded + nb - 1) / nb;
        repack_pos<<<rg, nb, 0, stream>>>(pos, pos4, gcnt, n_nodes, padded);

        int ga = (int)((n_edges + (long)NSTAGE - 1) / (long)NSTAGE);
        phaseA<<<ga, BLKA, 0, stream>>>(edst, esrc, gcnt, recs,
                                        n_edges, capx, n_chunk);
        phaseB<<<n_chunk * SHARDS, BLKB, 0, stream>>>(gcnt, recs, pos4, accR,
                                                      capx, n_chunk, padded);
        finalize_binned<<<ng, nb, 0, stream>>>(accR, feat, w0, w1,
                                               (float*)d_out, n_nodes, padded);
    } else {
        int R = 4;
        while (R > 1 && (size_t)R * n_nodes * sizeof(unsigned long long) > ws_size) R >>= 1;
        unsigned long long* acc = (unsigned long long*)d_ws;
        hipMemsetAsync(acc, 0, (size_t)R * n_nodes * sizeof(unsigned long long), stream);
        int eb = 256;
        int eg = (n_edges + eb - 1) / eb;
        edge_kernel_agent<<<eg, eb, 0, stream>>>(pos, edst, esrc, acc,
                                                 n_edges, n_nodes, R - 1);
        finalize_flat<<<ng, nb, 0, stream>>>(acc, feat, w0, w1,
                                             (float*)d_out, n_nodes, R);
    }
}